// Round 8
// baseline (549.242 us; speedup 1.0000x reference)
//
#include <hip/hip_runtime.h>
#include <hip/hip_fp16.h>
#include <math.h>

#define NNODES 100000
#define NEDGES 1600000
#define NGRAPH 256
#define NCONV  3
#define TBL    4096
#define CHUNK  512
#define NCHUNK 196         // ceil(100000/512)
#define CAP    9216        // fixed per-chunk region capacity (mean 8163 + 11 sigma)
#define R_MIN_ 1.0f
#define R_MAX_ 6.0f
#define LOG2E  1.4426950408889634f

typedef _Float16 f16x8 __attribute__((ext_vector_type(8)));
typedef float f32x4 __attribute__((ext_vector_type(4)));
union HF { float4 f4; f16x8 h8; __half2 q[4]; };

__device__ __forceinline__ float softplus_f(float x){
  return fmaxf(x, 0.f) + __logf(1.f + __expf(-fabsf(x)));
}

// ---------------- fused prep ----------------
// b in [0,64):    Wm1/Wm2 MFMA b-fragment pack
// b == 64:        softplus LUT + ccur/gsum/gcnt init
// b in [65,257):  conv weight pack WmC
// b >= 257:       embedding gather
__global__ void k_prep(const int* __restrict__ numbers, const float* __restrict__ embed,
                       float* __restrict__ x,
                       const float* __restrict__ Wf, const float* __restrict__ Ws,
                       __half* __restrict__ WmC,
                       const float* __restrict__ W1, const float* __restrict__ W2,
                       __half* __restrict__ Wm1, __half* __restrict__ Wm2,
                       float2* __restrict__ lutg, int* __restrict__ ccur,
                       float* __restrict__ gsum, int* __restrict__ gcnt){
  int b = blockIdx.x, t = threadIdx.x;
  if (b >= 257){
    int i = (b - 257)*256 + t;
    if (i < NNODES*64){
      int n = i >> 6, c = i & 63;
      x[i] = embed[numbers[n]*64 + c];
    }
    return;
  }
  if (b >= 65){
    // WmC[i]: [ct(16)][kt(2)][lane(64)][e(8)]; cols 0..63 pf, 64..127 ps, 128..191 qf, 192..255 qs
    int idx = (b - 65)*256 + t;       // < 3*16384
    int i = idx / 16384;
    int rem = idx & 16383;
    int ct = rem >> 10;
    int kt = (rem >> 9) & 1;
    int lane = (rem >> 3) & 63;
    int e = rem & 7;
    int col = ct*16 + (lane & 15);
    int part = col >> 6;
    int ch = col & 63;
    int k = kt*32 + (lane >> 4)*8 + e;
    int row = ((part >> 1) ? 64 : 0) + k;
    const float* W = ((part & 1) ? Ws : Wf) + i*192*64;
    WmC[idx] = __float2half_rn(W[row*64 + ch]);
    return;
  }
  if (b == 64){
    __shared__ float cv[513];
    for (int i = t; i < 513; i += 256){
      float z = -16.f + (float)i * (1.f/16.f);
      cv[i] = log2f(1.f + exp2f(z));
    }
    __syncthreads();
    for (int i = t; i < 512; i += 256)
      lutg[i] = make_float2(cv[i], cv[i+1]-cv[i]);
    if (t < NCHUNK) ccur[t] = t * CAP;
    if (t < NGRAPH){ gsum[t] = 0.f; gcnt[t] = 0; }
    return;
  }
  int i = b*256 + t;                 // [0, 16384)
  if (i < 8192){
    int ct = i >> 10;
    int kt = (i >> 9) & 1;
    int lane = (i >> 3) & 63;
    int e = i & 7;
    int k = kt*32 + (lane>>4)*8 + e;
    int c = ct*16 + (lane&15);
    Wm1[i] = __float2half_rn(W1[k*128 + c]);
  }
  {
    int ct = i >> 11;
    int kt = (i >> 9) & 3;
    int lane = (i >> 3) & 63;
    int e = i & 7;
    int k = kt*32 + (lane>>4)*8 + e;
    int c = ct*16 + (lane&15);
    Wm2[i] = __float2half_rn(W2[k*128 + c]);
  }
}

// ---------------- pass 1: bin edges into fixed-stride chunk regions ----------------
__global__ void k_bin(const int* __restrict__ src, const int* __restrict__ tgt,
                      const float* __restrict__ elen, int* ccur,
                      int2* __restrict__ eb){
  __shared__ int lcnt[NCHUNK];
  __shared__ int lbase[NCHUNK];
  __shared__ int loff[NCHUNK];
  int t = threadIdx.x;
  int e0 = blockIdx.x * 2048;
  if (t < NCHUNK){ lcnt[t] = 0; loff[t] = 0; }
  __syncthreads();
  #pragma unroll
  for (int k = 0; k < 8; k++){
    int e = e0 + k*256 + t;
    if (e < NEDGES) atomicAdd(&lcnt[src[e] / CHUNK], 1);
  }
  __syncthreads();
  if (t < NCHUNK && lcnt[t] > 0) lbase[t] = atomicAdd(&ccur[t], lcnt[t]);
  __syncthreads();
  #pragma unroll
  for (int k = 0; k < 8; k++){
    int e = e0 + k*256 + t;
    if (e < NEDGES){
      int s = src[e];
      int c = s / CHUNK;
      int r = atomicAdd(&loff[c], 1);
      float key = (elen[e] - R_MIN_) * ((float)(TBL-1)/(R_MAX_-R_MIN_));
      key = fmaxf(key, 0.f);
      int idx = (int)(key + 0.5f);
      if (idx > TBL-1) idx = TBL-1;
      eb[lbase[c] + r] = make_int2(((s & (CHUNK-1)) << 17) | tgt[e], idx);
    }
  }
}

// ---------------- pass 2: fine scatter; builds offs + deg via LDS count+scan ----------------
__global__ void k_fine(const int* __restrict__ ccur, const int2* __restrict__ eb,
                       int2* __restrict__ ep, int* __restrict__ offs,
                       int* __restrict__ deg){
  __shared__ int lcnt[CHUNK];
  __shared__ int lsc[CHUNK];
  int c = blockIdx.x;
  int t = threadIdx.x;                    // 512 threads
  int n0 = c * CHUNK;
  int n1 = min(n0 + CHUNK, NNODES);
  int cnt = n1 - n0;
  int j0 = c * CAP;
  int j1 = ccur[c];                       // j0 + edges in this chunk
  lcnt[t] = 0;
  __syncthreads();
  for (int e = j0 + t; e < j1; e += 512)
    atomicAdd(&lcnt[((unsigned)eb[e].x) >> 17], 1);
  __syncthreads();
  lsc[t] = lcnt[t];
  __syncthreads();
  for (int d = 1; d < 512; d <<= 1){
    int v = (t >= d) ? lsc[t-d] : 0;
    __syncthreads();
    lsc[t] += v;
    __syncthreads();
  }
  int excl = lsc[t] - lcnt[t];
  if (t < cnt){ offs[n0 + t] = j0 + excl; deg[n0 + t] = lcnt[t]; }
  __syncthreads();
  lcnt[t] = j0 + excl;                    // reuse as cursors
  __syncthreads();
  for (int e = j0 + t; e < j1; e += 512){
    int2 rec = eb[e];
    int sl = ((unsigned)rec.x) >> 17;
    int pos = atomicAdd(&lcnt[sl], 1);
    ep[pos] = make_int2(rec.x & 0x1FFFF, rec.y);
  }
}

// ---------------- Gaussian table, fp16, PRE-SCALED by log2(e) ----------------
__global__ void k_gauss(const float* __restrict__ Wf, const float* __restrict__ bf,
                        const float* __restrict__ Ws, const float* __restrict__ bs,
                        __half* __restrict__ Gth){
  __shared__ float attr[64];
  int bi = blockIdx.x;                  // 3*TBL
  int i = bi / TBL, r = bi % TBL;
  int t = threadIdx.x;                  // 128
  float d = R_MIN_ + (R_MAX_-R_MIN_) * (float)r / (float)(TBL-1);
  if (t < 64){
    float cj = 1.f + 5.f * (float)t / 63.f;
    float u = (d - cj) * (64.f/5.f);
    attr[t] = __expf(-0.5f*u*u);
  }
  __syncthreads();
  int c = t >> 1;
  int side = t & 1;
  const float* W = (side ? Ws : Wf) + i*192*64 + 128*64 + c;
  float acc = (side ? bs : bf)[i*64 + c];
  #pragma unroll 8
  for (int j = 0; j < 64; j++) acc = fmaf(attr[j], W[j*64], acc);
  Gth[((size_t)i*TBL + r)*128 + t] = __float2half_rn(acc * LOG2E);
}

// ---------------- node transform via MFMA: 32 nodes x 256 cols ----------------
__global__ void k_ntrans(const float* __restrict__ x, const __half* __restrict__ WmC,
                         __half2* __restrict__ pqh){
  __shared__ __half xh[32*72];      // 4.5 KB, row stride 72
  int n0 = blockIdx.x * 32;         // 3125 blocks
  int t = threadIdx.x;              // 256 = 4 waves
  int w = t >> 6, lane = t & 63;
  int lg = lane >> 4, lc = lane & 15;
  {
    int n = t >> 3, g = t & 7;
    const float4* xp = (const float4*)(x + (size_t)(n0 + n)*64 + g*8);
    float4 a = xp[0], b = xp[1];
    HF hh;
    hh.q[0] = __float22half2_rn(make_float2(a.x, a.y));
    hh.q[1] = __float22half2_rn(make_float2(a.z, a.w));
    hh.q[2] = __float22half2_rn(make_float2(b.x, b.y));
    hh.q[3] = __float22half2_rn(make_float2(b.z, b.w));
    *(float4*)(xh + n*72 + g*8) = hh.f4;
  }
  __syncthreads();
  HF a[2][2];
  #pragma unroll
  for (int m = 0; m < 2; m++)
    #pragma unroll
    for (int kt = 0; kt < 2; kt++)
      a[m][kt].f4 = *(const float4*)(xh + (m*16 + lc)*72 + kt*32 + lg*8);
  const float4* wb = (const float4*)WmC;
  f32x4 acc[4][2];                  // [part][m]
  #pragma unroll
  for (int p4 = 0; p4 < 4; p4++){
    int ct = p4*4 + w;
    HF b0, b1;
    b0.f4 = wb[(ct*2 + 0)*64 + lane];
    b1.f4 = wb[(ct*2 + 1)*64 + lane];
    #pragma unroll
    for (int m = 0; m < 2; m++){
      f32x4 c = {0.f, 0.f, 0.f, 0.f};
      c = __builtin_amdgcn_mfma_f32_16x16x32_f16(a[m][0].h8, b0.h8, c, 0, 0, 0);
      c = __builtin_amdgcn_mfma_f32_16x16x32_f16(a[m][1].h8, b1.h8, c, 0, 0, 0);
      acc[p4][m] = c;
    }
  }
  #pragma unroll
  for (int m = 0; m < 2; m++)
    #pragma unroll
    for (int r = 0; r < 4; r++){
      int node = n0 + m*16 + lg*4 + r;
      int ch = w*16 + lc;
      __half2 hp = __floats2half2_rn(acc[0][m][r]*LOG2E, acc[1][m][r]*LOG2E);
      __half2 hq = __floats2half2_rn(acc[2][m][r]*LOG2E, acc[3][m][r]*LOG2E);
      pqh[(size_t)node*128 + ch]      = hp;
      pqh[(size_t)node*128 + 64 + ch] = hq;
    }
}

// ---------------- edge pass: wave per node; all edges through ILP-8 batches ----------------
// Final partial batch uses s_min-clamped record addresses + per-edge 0/1 mask (exact).
// sig = rcp(1 + 2^-(pf+z.x));  sp/ln2 = max(zs, T_lut(zs))
__global__ void k_edge(const __half2* __restrict__ pqh,
                       const int* __restrict__ offs, const int* __restrict__ deg,
                       const int2* __restrict__ ep,
                       const __half* __restrict__ Gth, const float* __restrict__ lng,
                       const float* __restrict__ lnb, const float2* __restrict__ lutg,
                       float* __restrict__ x){
  __shared__ float2 lut[512];       // 4 KB softplus-T table
  {
    ((float4*)lut)[threadIdx.x] = ((const float4*)lutg)[threadIdx.x];
  }
  __syncthreads();
  int wid  = (blockIdx.x*256 + threadIdx.x) >> 6;
  int lane = threadIdx.x & 63;
  int n = wid;
  int j0 = __builtin_amdgcn_readfirstlane(offs[n]);
  int dg = __builtin_amdgcn_readfirstlane(deg[n]);
  int j1 = j0 + dg;
  int nb = (dg + 7) >> 3;           // total batches (incl. masked final)
  int jl = j1 - 1;                  // clamp target (valid when dg>0)
  int2 eb8[8];
  if (nb > 0){
    #pragma unroll
    for (int i = 0; i < 8; i++) eb8[i] = ep[min(j0 + i, jl)];
  }
  float2 pp = __half22float2(pqh[(size_t)n*128 + lane]);
  float pf = pp.x, ps = pp.y;
  float pso = fmaf(ps, 16.f, 256.f);     // T-table index offset (f32-precise p add)
  const char* pqb = (const char*)pqh;
  const char* gtb = (const char*)Gth;
  unsigned qob = 256u + ((unsigned)lane << 2);
  unsigned lob = (unsigned)lane << 2;
  float acc = 0.f;
  for (int b = 0; b < nb; b++){
    int base = j0 + b*8;
    __half2 qr[8], gr[8];
    #pragma unroll
    for (int i = 0; i < 8; i++){
      qr[i] = *(const __half2*)(pqb + ((((unsigned)eb8[i].x) << 9) + qob));
      gr[i] = *(const __half2*)(gtb + ((((unsigned)eb8[i].y) << 8) + lob));
    }
    if (b + 1 < nb){
      #pragma unroll
      for (int i = 0; i < 8; i++) eb8[i] = ep[min(base + 8 + i, jl)];
    }
    if (base + 8 <= j1){
      #pragma unroll
      for (int i = 0; i < 8; i++){
        float2 z = __half22float2(__hadd2(qr[i], gr[i]));
        float sig = __builtin_amdgcn_rcpf(1.f + __builtin_amdgcn_exp2f(-(pf + z.x)));
        float xj = __builtin_amdgcn_fmed3f(fmaf(z.y, 16.f, pso), 0.f, 511.36f);
        int i2 = (int)xj;
        float f2 = __builtin_amdgcn_fractf(xj);
        float2 e2 = lut[i2];
        float zs = ps + z.y;
        float sp = fmaxf(zs, fmaf(e2.y, f2, e2.x));
        acc = fmaf(sig, sp, acc);
      }
    } else {
      int rem = j1 - base;          // 1..7, wave-uniform
      #pragma unroll
      for (int i = 0; i < 8; i++){
        float m = (i < rem) ? 1.f : 0.f;
        float2 z = __half22float2(__hadd2(qr[i], gr[i]));
        float sig = __builtin_amdgcn_rcpf(1.f + __builtin_amdgcn_exp2f(-(pf + z.x)));
        float xj = __builtin_amdgcn_fmed3f(fmaf(z.y, 16.f, pso), 0.f, 511.36f);
        int i2 = (int)xj;
        float f2 = __builtin_amdgcn_fractf(xj);
        float2 e2 = lut[i2];
        float zs = ps + z.y;
        float sp = fmaxf(zs, fmaf(e2.y, f2, e2.x));
        acc = fmaf(sig * m, sp, acc);
      }
    }
  }
  float s1 = acc, s2 = acc*acc;
  #pragma unroll
  for (int o = 32; o > 0; o >>= 1){ s1 += __shfl_xor(s1, o, 64); s2 += __shfl_xor(s2, o, 64); }
  float mu  = s1 * (1.f/64.f);
  float var = s2 * (1.f/64.f) - mu*mu;
  float inv = rsqrtf(fmaxf(var, 0.f) + 1e-5f);
  float y = (acc - mu) * inv * lng[lane] + lnb[lane];
  x[(size_t)n*64 + lane] += y;
}

// ---------------- fused head: MFMA 16x16x32 f16 GEMMs + LN/softplus epilogues ----------------
__global__ void k_head(const float* __restrict__ x,
                       const __half* __restrict__ Wm1, const float* __restrict__ b1,
                       const float* __restrict__ g1, const float* __restrict__ bt1,
                       const __half* __restrict__ Wm2, const float* __restrict__ b2,
                       const float* __restrict__ g2, const float* __restrict__ bt2,
                       const float* __restrict__ Wout, const int* __restrict__ batch,
                       float* gsum, int* gcnt){
  __shared__ __half xh[32*72];      // 4.5 KB
  __shared__ __half hs[32*136];     // 8.5 KB
  __shared__ float red[4][32][2];
  __shared__ float stat[32][2];
  __shared__ float es[32];
  int n0 = blockIdx.x * 32;         // 3125 blocks
  int t = threadIdx.x;              // 256
  int w = t >> 6, lane = t & 63;
  int lg = lane >> 4, lc = lane & 15;
  int col0 = w*32 + lc, col1 = w*32 + 16 + lc;

  {
    int n = t >> 3, g = t & 7;
    const float4* xp = (const float4*)(x + (size_t)(n0 + n)*64 + g*8);
    float4 a = xp[0], b = xp[1];
    HF hh;
    hh.q[0] = __float22half2_rn(make_float2(a.x, a.y));
    hh.q[1] = __float22half2_rn(make_float2(a.z, a.w));
    hh.q[2] = __float22half2_rn(make_float2(b.x, b.y));
    hh.q[3] = __float22half2_rn(make_float2(b.z, b.w));
    *(float4*)(xh + n*72 + g*8) = hh.f4;
  }
  __syncthreads();

  // ---- layer 1: 64 -> 128 via MFMA ----
  f32x4 acc[2][2];
  {
    HF a[2][2], b[2][2];
    #pragma unroll
    for (int m = 0; m < 2; m++)
      #pragma unroll
      for (int kt = 0; kt < 2; kt++)
        a[m][kt].f4 = *(const float4*)(xh + (m*16 + lc)*72 + kt*32 + lg*8);
    const float4* wb = (const float4*)Wm1;
    #pragma unroll
    for (int ct = 0; ct < 2; ct++)
      #pragma unroll
      for (int kt = 0; kt < 2; kt++)
        b[ct][kt].f4 = wb[(((w*2 + ct)*2 + kt)*64) + lane];
    #pragma unroll
    for (int m = 0; m < 2; m++)
      #pragma unroll
      for (int ct = 0; ct < 2; ct++){
        f32x4 c = {0.f, 0.f, 0.f, 0.f};
        c = __builtin_amdgcn_mfma_f32_16x16x32_f16(a[m][0].h8, b[ct][0].h8, c, 0, 0, 0);
        c = __builtin_amdgcn_mfma_f32_16x16x32_f16(a[m][1].h8, b[ct][1].h8, c, 0, 0, 0);
        acc[m][ct] = c;
      }
  }
  {
    float bv0 = b1[col0], bv1 = b1[col1];
    #pragma unroll
    for (int m = 0; m < 2; m++)
      #pragma unroll
      for (int r = 0; r < 4; r++){
        acc[m][0][r] += bv0; acc[m][1][r] += bv1;
        float a0 = acc[m][0][r], a1 = acc[m][1][r];
        float s1 = a0 + a1, s2 = a0*a0 + a1*a1;
        #pragma unroll
        for (int o = 1; o < 16; o <<= 1){ s1 += __shfl_xor(s1, o, 64); s2 += __shfl_xor(s2, o, 64); }
        if (lc == 0){ int row = m*16 + lg*4 + r; red[w][row][0] = s1; red[w][row][1] = s2; }
      }
  }
  __syncthreads();
  if (t < 32){
    float s1 = red[0][t][0] + red[1][t][0] + red[2][t][0] + red[3][t][0];
    float s2 = red[0][t][1] + red[1][t][1] + red[2][t][1] + red[3][t][1];
    float mu = s1 * (1.f/128.f);
    float var = s2 * (1.f/128.f) - mu*mu;
    stat[t][0] = mu;
    stat[t][1] = rsqrtf(fmaxf(var, 0.f) + 1e-5f);
  }
  __syncthreads();
  {
    float g1a = g1[col0], g1b = g1[col1], b1a = bt1[col0], b1b = bt1[col1];
    #pragma unroll
    for (int m = 0; m < 2; m++)
      #pragma unroll
      for (int r = 0; r < 4; r++){
        int row = m*16 + lg*4 + r;
        float mu = stat[row][0], inv = stat[row][1];
        float y0 = (acc[m][0][r] - mu)*inv*g1a + b1a;
        float y1 = (acc[m][1][r] - mu)*inv*g1b + b1b;
        hs[row*136 + col0] = __float2half_rn(softplus_f(y0));
        hs[row*136 + col1] = __float2half_rn(softplus_f(y1));
      }
  }
  __syncthreads();

  // ---- layer 2: 128 -> 128 via MFMA ----
  f32x4 acc2[2][2];
  {
    HF b[2][4];
    const float4* wb = (const float4*)Wm2;
    #pragma unroll
    for (int ct = 0; ct < 2; ct++)
      #pragma unroll
      for (int kt = 0; kt < 4; kt++)
        b[ct][kt].f4 = wb[(((w*2 + ct)*4 + kt)*64) + lane];
    #pragma unroll
    for (int m = 0; m < 2; m++){
      f32x4 c0 = {0.f,0.f,0.f,0.f}, c1 = {0.f,0.f,0.f,0.f};
      #pragma unroll
      for (int kt = 0; kt < 4; kt++){
        HF av; av.f4 = *(const float4*)(hs + (m*16 + lc)*136 + kt*32 + lg*8);
        c0 = __builtin_amdgcn_mfma_f32_16x16x32_f16(av.h8, b[0][kt].h8, c0, 0, 0, 0);
        c1 = __builtin_amdgcn_mfma_f32_16x16x32_f16(av.h8, b[1][kt].h8, c1, 0, 0, 0);
      }
      acc2[m][0] = c0; acc2[m][1] = c1;
    }
  }
  {
    float bv0 = b2[col0], bv1 = b2[col1];
    #pragma unroll
    for (int m = 0; m < 2; m++)
      #pragma unroll
      for (int r = 0; r < 4; r++){
        acc2[m][0][r] += bv0; acc2[m][1][r] += bv1;
        float a0 = acc2[m][0][r], a1 = acc2[m][1][r];
        float s1 = a0 + a1, s2 = a0*a0 + a1*a1;
        #pragma unroll
        for (int o = 1; o < 16; o <<= 1){ s1 += __shfl_xor(s1, o, 64); s2 += __shfl_xor(s2, o, 64); }
        if (lc == 0){ int row = m*16 + lg*4 + r; red[w][row][0] = s1; red[w][row][1] = s2; }
      }
  }
  __syncthreads();
  if (t < 32){
    float s1 = red[0][t][0] + red[1][t][0] + red[2][t][0] + red[3][t][0];
    float s2 = red[0][t][1] + red[1][t][1] + red[2][t][1] + red[3][t][1];
    float mu = s1 * (1.f/128.f);
    float var = s2 * (1.f/128.f) - mu*mu;
    stat[t][0] = mu;
    stat[t][1] = rsqrtf(fmaxf(var, 0.f) + 1e-5f);
  }
  __syncthreads();
  {
    float g2a = g2[col0], g2b = g2[col1], b2a = bt2[col0], b2b = bt2[col1];
    float woa = Wout[col0], wob = Wout[col1];
    #pragma unroll
    for (int m = 0; m < 2; m++)
      #pragma unroll
      for (int r = 0; r < 4; r++){
        int row = m*16 + lg*4 + r;
        float mu = stat[row][0], inv = stat[row][1];
        float e = softplus_f((acc2[m][0][r] - mu)*inv*g2a + b2a) * woa
                + softplus_f((acc2[m][1][r] - mu)*inv*g2b + b2b) * wob;
        #pragma unroll
        for (int o = 1; o < 16; o <<= 1) e += __shfl_xor(e, o, 64);
        if (lc == 0) red[w][row][0] = e;
      }
  }
  __syncthreads();
  if (t < 32) es[t] = red[0][t][0] + red[1][t][0] + red[2][t][0] + red[3][t][0];
  __syncthreads();

  if (t < 32){
    int node = n0 + t;
    int g = batch[node];
    bool head = (t == 0) || (batch[node-1] != g);
    if (head){
      float s = 0.f; int c = 0;
      int j = t;
      while (j < 32 && batch[n0+j] == g){ s += es[j]; c++; j++; }
      atomicAdd(&gsum[g], s);
      atomicAdd(&gcnt[g], c);
    }
  }
}

// ---------------- final ----------------
__global__ void k_final(const float* __restrict__ gsum, const int* __restrict__ gcnt,
                        const float* __restrict__ bout, float* __restrict__ out){
  int g = threadIdx.x;
  if (g < NGRAPH)
    out[g] = gsum[g] / fmaxf((float)gcnt[g], 1.f) + bout[0];
}

extern "C" void kernel_launch(void* const* d_in, const int* in_sizes, int n_in,
                              void* d_out, int out_size, void* d_ws, size_t ws_size,
                              hipStream_t stream){
  const int*   numbers = (const int*)d_in[0];
  const int*   eidx    = (const int*)d_in[1];
  const float* elen    = (const float*)d_in[2];
  const int*   batch   = (const int*)d_in[3];
  const float* embed   = (const float*)d_in[4];
  const float* Wf      = (const float*)d_in[5];
  const float* bf      = (const float*)d_in[6];
  const float* Ws      = (const float*)d_in[7];
  const float* bs      = (const float*)d_in[8];
  const float* lng     = (const float*)d_in[9];
  const float* lnb     = (const float*)d_in[10];
  const float* W1      = (const float*)d_in[11];
  const float* b1      = (const float*)d_in[12];
  const float* g1      = (const float*)d_in[13];
  const float* bt1     = (const float*)d_in[14];
  const float* W2      = (const float*)d_in[15];
  const float* b2      = (const float*)d_in[16];
  const float* g2      = (const float*)d_in[17];
  const float* bt2     = (const float*)d_in[18];
  const float* Wout    = (const float*)d_in[19];
  const float* bout    = (const float*)d_in[20];
  const int* src = eidx;
  const int* tgt = eidx + NEDGES;

  float*   x    = (float*)d_ws;                          // N*64 f32
  __half2* pqh  = (__half2*)(x + (size_t)NNODES*64);     // N*128 half2
  __half*  Gth  = (__half*)(pqh + (size_t)NNODES*128);   // 3*TBL*128 half
  __half*  WmC  = Gth + (size_t)3*TBL*128;               // 3*16384 half
  __half*  Wm1  = WmC + (size_t)3*16384;                 // 8192 half
  __half*  Wm2  = Wm1 + 8192;                            // 16384 half
  float2*  lutg = (float2*)(Wm2 + 16384);                // 1024 float2 (512 used)
  int2*    ep   = (int2*)(lutg + 1024);                  // NCHUNK*CAP int2 (final CSR)
  int2*    ebuf = ep + (size_t)NCHUNK*CAP;               // NCHUNK*CAP int2 (staging)
  int*     offs = (int*)(ebuf + (size_t)NCHUNK*CAP);     // N
  int*     deg  = offs + NNODES;                         // N
  int*     ccur = deg + NNODES;                          // 256
  float*   gsum = (float*)(ccur + 256);                  // 256
  int*     gcnt = (int*)(gsum + NGRAPH);                 // 256
  float*   out  = (float*)d_out;

  k_prep  <<<257 + (NNODES*64+255)/256, 256, 0, stream>>>(
            numbers, embed, x, Wf, Ws, WmC, W1, W2, Wm1, Wm2,
            lutg, ccur, gsum, gcnt);

  k_bin   <<<(NEDGES+2047)/2048, 256, 0, stream>>>(src, tgt, elen, ccur, ebuf);
  k_fine  <<<NCHUNK, 512, 0, stream>>>(ccur, ebuf, ep, offs, deg);

  k_gauss <<<3*TBL, 128, 0, stream>>>(Wf, bf, Ws, bs, Gth);

  for (int i = 0; i < NCONV; i++){
    k_ntrans<<<NNODES/32, 256, 0, stream>>>(x, WmC + (size_t)i*16384, pqh);
    k_edge  <<<NNODES/4, 256, 0, stream>>>(pqh, offs, deg, ep,
                                           Gth + (size_t)i*TBL*128,
                                           lng + i*64, lnb + i*64, lutg, x);
  }

  k_head<<<NNODES/32, 256, 0, stream>>>(x, Wm1, b1, g1, bt1,
                                        Wm2, b2, g2, bt2, Wout, batch, gsum, gcnt);
  k_final<<<1, 256, 0, stream>>>(gsum, gcnt, bout, out);
}

// Round 9
// 542.033 us; speedup vs baseline: 1.0133x; 1.0133x over previous
//
#include <hip/hip_runtime.h>
#include <hip/hip_fp16.h>
#include <math.h>

#define NNODES 100000
#define NEDGES 1600000
#define NGRAPH 256
#define NCONV  3
#define TBL    4096
#define CHUNK  512
#define NCHUNK 196         // ceil(100000/512)
#define CAP    9216        // fixed per-chunk region capacity (mean 8163 + 11 sigma)
#define R_MIN_ 1.0f
#define R_MAX_ 6.0f
#define LOG2E  1.4426950408889634f

typedef _Float16 f16x8 __attribute__((ext_vector_type(8)));
typedef float f32x4 __attribute__((ext_vector_type(4)));
union HF { float4 f4; f16x8 h8; __half2 q[4]; };

__device__ __forceinline__ float softplus_f(float x){
  return fmaxf(x, 0.f) + __logf(1.f + __expf(-fabsf(x)));
}

// ---------------- fused prep ----------------
// b in [0,64):    Wm1/Wm2 MFMA b-fragment pack
// b == 64:        softplus LUT + ccur/gsum/gcnt init
// b in [65,257):  conv weight pack WmC
// b >= 257:       embedding gather
__global__ void k_prep(const int* __restrict__ numbers, const float* __restrict__ embed,
                       float* __restrict__ x,
                       const float* __restrict__ Wf, const float* __restrict__ Ws,
                       __half* __restrict__ WmC,
                       const float* __restrict__ W1, const float* __restrict__ W2,
                       __half* __restrict__ Wm1, __half* __restrict__ Wm2,
                       float2* __restrict__ lutg, int* __restrict__ ccur,
                       float* __restrict__ gsum, int* __restrict__ gcnt){
  int b = blockIdx.x, t = threadIdx.x;
  if (b >= 257){
    int i = (b - 257)*256 + t;
    if (i < NNODES*64){
      int n = i >> 6, c = i & 63;
      x[i] = embed[numbers[n]*64 + c];
    }
    return;
  }
  if (b >= 65){
    // WmC[i]: [ct(16)][kt(2)][lane(64)][e(8)]; cols 0..63 pf, 64..127 ps, 128..191 qf, 192..255 qs
    int idx = (b - 65)*256 + t;       // < 3*16384
    int i = idx / 16384;
    int rem = idx & 16383;
    int ct = rem >> 10;
    int kt = (rem >> 9) & 1;
    int lane = (rem >> 3) & 63;
    int e = rem & 7;
    int col = ct*16 + (lane & 15);
    int part = col >> 6;
    int ch = col & 63;
    int k = kt*32 + (lane >> 4)*8 + e;
    int row = ((part >> 1) ? 64 : 0) + k;
    const float* W = ((part & 1) ? Ws : Wf) + i*192*64;
    WmC[idx] = __float2half_rn(W[row*64 + ch]);
    return;
  }
  if (b == 64){
    __shared__ float cv[513];
    for (int i = t; i < 513; i += 256){
      float z = -16.f + (float)i * (1.f/16.f);
      cv[i] = log2f(1.f + exp2f(z));
    }
    __syncthreads();
    for (int i = t; i < 512; i += 256)
      lutg[i] = make_float2(cv[i], cv[i+1]-cv[i]);
    if (t < NCHUNK) ccur[t] = t * CAP;
    if (t < NGRAPH){ gsum[t] = 0.f; gcnt[t] = 0; }
    return;
  }
  int i = b*256 + t;                 // [0, 16384)
  if (i < 8192){
    int ct = i >> 10;
    int kt = (i >> 9) & 1;
    int lane = (i >> 3) & 63;
    int e = i & 7;
    int k = kt*32 + (lane>>4)*8 + e;
    int c = ct*16 + (lane&15);
    Wm1[i] = __float2half_rn(W1[k*128 + c]);
  }
  {
    int ct = i >> 11;
    int kt = (i >> 9) & 3;
    int lane = (i >> 3) & 63;
    int e = i & 7;
    int k = kt*32 + (lane>>4)*8 + e;
    int c = ct*16 + (lane&15);
    Wm2[i] = __float2half_rn(W2[k*128 + c]);
  }
}

// ---------------- pass 1: bin edges into fixed-stride chunk regions ----------------
__global__ void k_bin(const int* __restrict__ src, const int* __restrict__ tgt,
                      const float* __restrict__ elen, int* ccur,
                      int2* __restrict__ eb){
  __shared__ int lcnt[NCHUNK];
  __shared__ int lbase[NCHUNK];
  __shared__ int loff[NCHUNK];
  int t = threadIdx.x;
  int e0 = blockIdx.x * 2048;
  if (t < NCHUNK){ lcnt[t] = 0; loff[t] = 0; }
  __syncthreads();
  #pragma unroll
  for (int k = 0; k < 8; k++){
    int e = e0 + k*256 + t;
    if (e < NEDGES) atomicAdd(&lcnt[src[e] / CHUNK], 1);
  }
  __syncthreads();
  if (t < NCHUNK && lcnt[t] > 0) lbase[t] = atomicAdd(&ccur[t], lcnt[t]);
  __syncthreads();
  #pragma unroll
  for (int k = 0; k < 8; k++){
    int e = e0 + k*256 + t;
    if (e < NEDGES){
      int s = src[e];
      int c = s / CHUNK;
      int r = atomicAdd(&loff[c], 1);
      float key = (elen[e] - R_MIN_) * ((float)(TBL-1)/(R_MAX_-R_MIN_));
      key = fmaxf(key, 0.f);
      int idx = (int)(key + 0.5f);
      if (idx > TBL-1) idx = TBL-1;
      eb[lbase[c] + r] = make_int2(((s & (CHUNK-1)) << 17) | tgt[e], idx);
    }
  }
}

// ---------------- pass 2: fine scatter; builds offs + deg via LDS count+scan ----------------
__global__ void k_fine(const int* __restrict__ ccur, const int2* __restrict__ eb,
                       int2* __restrict__ ep, int* __restrict__ offs,
                       int* __restrict__ deg){
  __shared__ int lcnt[CHUNK];
  __shared__ int lsc[CHUNK];
  int c = blockIdx.x;
  int t = threadIdx.x;                    // 512 threads
  int n0 = c * CHUNK;
  int n1 = min(n0 + CHUNK, NNODES);
  int cnt = n1 - n0;
  int j0 = c * CAP;
  int j1 = ccur[c];                       // j0 + edges in this chunk
  lcnt[t] = 0;
  __syncthreads();
  for (int e = j0 + t; e < j1; e += 512)
    atomicAdd(&lcnt[((unsigned)eb[e].x) >> 17], 1);
  __syncthreads();
  lsc[t] = lcnt[t];
  __syncthreads();
  for (int d = 1; d < 512; d <<= 1){
    int v = (t >= d) ? lsc[t-d] : 0;
    __syncthreads();
    lsc[t] += v;
    __syncthreads();
  }
  int excl = lsc[t] - lcnt[t];
  if (t < cnt){ offs[n0 + t] = j0 + excl; deg[n0 + t] = lcnt[t]; }
  __syncthreads();
  lcnt[t] = j0 + excl;                    // reuse as cursors
  __syncthreads();
  for (int e = j0 + t; e < j1; e += 512){
    int2 rec = eb[e];
    int sl = ((unsigned)rec.x) >> 17;
    int pos = atomicAdd(&lcnt[sl], 1);
    ep[pos] = make_int2(rec.x & 0x1FFFF, rec.y);
  }
}

// ---------------- Gaussian table, fp16, PRE-SCALED by log2(e) ----------------
__global__ void k_gauss(const float* __restrict__ Wf, const float* __restrict__ bf,
                        const float* __restrict__ Ws, const float* __restrict__ bs,
                        __half* __restrict__ Gth){
  __shared__ float attr[64];
  int bi = blockIdx.x;                  // 3*TBL
  int i = bi / TBL, r = bi % TBL;
  int t = threadIdx.x;                  // 128
  float d = R_MIN_ + (R_MAX_-R_MIN_) * (float)r / (float)(TBL-1);
  if (t < 64){
    float cj = 1.f + 5.f * (float)t / 63.f;
    float u = (d - cj) * (64.f/5.f);
    attr[t] = __expf(-0.5f*u*u);
  }
  __syncthreads();
  int c = t >> 1;
  int side = t & 1;
  const float* W = (side ? Ws : Wf) + i*192*64 + 128*64 + c;
  float acc = (side ? bs : bf)[i*64 + c];
  #pragma unroll 8
  for (int j = 0; j < 64; j++) acc = fmaf(attr[j], W[j*64], acc);
  Gth[((size_t)i*TBL + r)*128 + t] = __float2half_rn(acc * LOG2E);
}

// ---------------- node transform via MFMA: 32 nodes x 256 cols ----------------
__global__ void k_ntrans(const float* __restrict__ x, const __half* __restrict__ WmC,
                         __half2* __restrict__ pqh){
  __shared__ __half xh[32*72];      // 4.5 KB, row stride 72
  int n0 = blockIdx.x * 32;         // 3125 blocks
  int t = threadIdx.x;              // 256 = 4 waves
  int w = t >> 6, lane = t & 63;
  int lg = lane >> 4, lc = lane & 15;
  {
    int n = t >> 3, g = t & 7;
    const float4* xp = (const float4*)(x + (size_t)(n0 + n)*64 + g*8);
    float4 a = xp[0], b = xp[1];
    HF hh;
    hh.q[0] = __float22half2_rn(make_float2(a.x, a.y));
    hh.q[1] = __float22half2_rn(make_float2(a.z, a.w));
    hh.q[2] = __float22half2_rn(make_float2(b.x, b.y));
    hh.q[3] = __float22half2_rn(make_float2(b.z, b.w));
    *(float4*)(xh + n*72 + g*8) = hh.f4;
  }
  __syncthreads();
  HF a[2][2];
  #pragma unroll
  for (int m = 0; m < 2; m++)
    #pragma unroll
    for (int kt = 0; kt < 2; kt++)
      a[m][kt].f4 = *(const float4*)(xh + (m*16 + lc)*72 + kt*32 + lg*8);
  const float4* wb = (const float4*)WmC;
  f32x4 acc[4][2];                  // [part][m]
  #pragma unroll
  for (int p4 = 0; p4 < 4; p4++){
    int ct = p4*4 + w;
    HF b0, b1;
    b0.f4 = wb[(ct*2 + 0)*64 + lane];
    b1.f4 = wb[(ct*2 + 1)*64 + lane];
    #pragma unroll
    for (int m = 0; m < 2; m++){
      f32x4 c = {0.f, 0.f, 0.f, 0.f};
      c = __builtin_amdgcn_mfma_f32_16x16x32_f16(a[m][0].h8, b0.h8, c, 0, 0, 0);
      c = __builtin_amdgcn_mfma_f32_16x16x32_f16(a[m][1].h8, b1.h8, c, 0, 0, 0);
      acc[p4][m] = c;
    }
  }
  #pragma unroll
  for (int m = 0; m < 2; m++)
    #pragma unroll
    for (int r = 0; r < 4; r++){
      int node = n0 + m*16 + lg*4 + r;
      int ch = w*16 + lc;
      __half2 hp = __floats2half2_rn(acc[0][m][r]*LOG2E, acc[1][m][r]*LOG2E);
      __half2 hq = __floats2half2_rn(acc[2][m][r]*LOG2E, acc[3][m][r]*LOG2E);
      pqh[(size_t)node*128 + ch]      = hp;
      pqh[(size_t)node*128 + 64 + ch] = hq;
    }
}

// ---------------- edge pass: wave per node; analytic sigmoid + softplus LUT ----------------
// (round-6 best-measured form: ILP-8 prefetched batches + plain serial tail)
// sig = rcp(1 + 2^-(pf+z.x));  sp/ln2 = max(zs, T_lut(zs))
__global__ void k_edge(const __half2* __restrict__ pqh,
                       const int* __restrict__ offs, const int* __restrict__ deg,
                       const int2* __restrict__ ep,
                       const __half* __restrict__ Gth, const float* __restrict__ lng,
                       const float* __restrict__ lnb, const float2* __restrict__ lutg,
                       float* __restrict__ x){
  __shared__ float2 lut[512];       // 4 KB softplus-T table
  {
    ((float4*)lut)[threadIdx.x] = ((const float4*)lutg)[threadIdx.x];
  }
  __syncthreads();
  int wid  = (blockIdx.x*256 + threadIdx.x) >> 6;
  int lane = threadIdx.x & 63;
  int n = wid;
  int j0 = __builtin_amdgcn_readfirstlane(offs[n]);
  int dg = __builtin_amdgcn_readfirstlane(deg[n]);
  int j1 = j0 + dg;
  int nfull = dg >> 3;
  int2 eb8[8];
  if (nfull > 0){
    #pragma unroll
    for (int i = 0; i < 8; i++) eb8[i] = ep[j0 + i];
  }
  float2 pp = __half22float2(pqh[(size_t)n*128 + lane]);
  float pf = pp.x, ps = pp.y;
  float pso = fmaf(ps, 16.f, 256.f);     // T-table index offset (f32-precise p add)
  const char* pqb = (const char*)pqh;
  const char* gtb = (const char*)Gth;
  unsigned qob = 256u + ((unsigned)lane << 2);
  unsigned lob = (unsigned)lane << 2;
  float acc = 0.f;
  int u = j0;
  for (int b = 0; b < nfull; b++){
    __half2 qr[8], gr[8];
    #pragma unroll
    for (int i = 0; i < 8; i++){
      qr[i] = *(const __half2*)(pqb + ((((unsigned)eb8[i].x) << 9) + qob));
      gr[i] = *(const __half2*)(gtb + ((((unsigned)eb8[i].y) << 8) + lob));
    }
    if (b + 1 < nfull){
      #pragma unroll
      for (int i = 0; i < 8; i++) eb8[i] = ep[u + 8 + i];
    }
    #pragma unroll
    for (int i = 0; i < 8; i++){
      float2 z = __half22float2(__hadd2(qr[i], gr[i]));
      float sig = __builtin_amdgcn_rcpf(1.f + __builtin_amdgcn_exp2f(-(pf + z.x)));
      float xj = __builtin_amdgcn_fmed3f(fmaf(z.y, 16.f, pso), 0.f, 511.36f);
      int i2 = (int)xj;
      float f2 = __builtin_amdgcn_fractf(xj);
      float2 e2 = lut[i2];
      float zs = ps + z.y;
      float sp = fmaxf(zs, fmaf(e2.y, f2, e2.x));
      acc = fmaf(sig, sp, acc);
    }
    u += 8;
  }
  for (; u < j1; u++){
    int2 e = ep[u];
    __half2 q = *(const __half2*)(pqb + ((((unsigned)e.x) << 9) + qob));
    __half2 g = *(const __half2*)(gtb + ((((unsigned)e.y) << 8) + lob));
    float2 z = __half22float2(__hadd2(q, g));
    float sig = __builtin_amdgcn_rcpf(1.f + __builtin_amdgcn_exp2f(-(pf + z.x)));
    float xj = __builtin_amdgcn_fmed3f(fmaf(z.y, 16.f, pso), 0.f, 511.36f);
    int i2 = (int)xj;
    float f2 = __builtin_amdgcn_fractf(xj);
    float2 e2 = lut[i2];
    float zs = ps + z.y;
    float sp = fmaxf(zs, fmaf(e2.y, f2, e2.x));
    acc = fmaf(sig, sp, acc);
  }
  float s1 = acc, s2 = acc*acc;
  #pragma unroll
  for (int o = 32; o > 0; o >>= 1){ s1 += __shfl_xor(s1, o, 64); s2 += __shfl_xor(s2, o, 64); }
  float mu  = s1 * (1.f/64.f);
  float var = s2 * (1.f/64.f) - mu*mu;
  float inv = rsqrtf(fmaxf(var, 0.f) + 1e-5f);
  float y = (acc - mu) * inv * lng[lane] + lnb[lane];
  x[(size_t)n*64 + lane] += y;
}

// ---------------- fused head: MFMA 16x16x32 f16 GEMMs + LN/softplus epilogues ----------------
__global__ void k_head(const float* __restrict__ x,
                       const __half* __restrict__ Wm1, const float* __restrict__ b1,
                       const float* __restrict__ g1, const float* __restrict__ bt1,
                       const __half* __restrict__ Wm2, const float* __restrict__ b2,
                       const float* __restrict__ g2, const float* __restrict__ bt2,
                       const float* __restrict__ Wout, const int* __restrict__ batch,
                       float* gsum, int* gcnt){
  __shared__ __half xh[32*72];      // 4.5 KB
  __shared__ __half hs[32*136];     // 8.5 KB
  __shared__ float red[4][32][2];
  __shared__ float stat[32][2];
  __shared__ float es[32];
  int n0 = blockIdx.x * 32;         // 3125 blocks
  int t = threadIdx.x;              // 256
  int w = t >> 6, lane = t & 63;
  int lg = lane >> 4, lc = lane & 15;
  int col0 = w*32 + lc, col1 = w*32 + 16 + lc;

  {
    int n = t >> 3, g = t & 7;
    const float4* xp = (const float4*)(x + (size_t)(n0 + n)*64 + g*8);
    float4 a = xp[0], b = xp[1];
    HF hh;
    hh.q[0] = __float22half2_rn(make_float2(a.x, a.y));
    hh.q[1] = __float22half2_rn(make_float2(a.z, a.w));
    hh.q[2] = __float22half2_rn(make_float2(b.x, b.y));
    hh.q[3] = __float22half2_rn(make_float2(b.z, b.w));
    *(float4*)(xh + n*72 + g*8) = hh.f4;
  }
  __syncthreads();

  // ---- layer 1: 64 -> 128 via MFMA ----
  f32x4 acc[2][2];
  {
    HF a[2][2], b[2][2];
    #pragma unroll
    for (int m = 0; m < 2; m++)
      #pragma unroll
      for (int kt = 0; kt < 2; kt++)
        a[m][kt].f4 = *(const float4*)(xh + (m*16 + lc)*72 + kt*32 + lg*8);
    const float4* wb = (const float4*)Wm1;
    #pragma unroll
    for (int ct = 0; ct < 2; ct++)
      #pragma unroll
      for (int kt = 0; kt < 2; kt++)
        b[ct][kt].f4 = wb[(((w*2 + ct)*2 + kt)*64) + lane];
    #pragma unroll
    for (int m = 0; m < 2; m++)
      #pragma unroll
      for (int ct = 0; ct < 2; ct++){
        f32x4 c = {0.f, 0.f, 0.f, 0.f};
        c = __builtin_amdgcn_mfma_f32_16x16x32_f16(a[m][0].h8, b[ct][0].h8, c, 0, 0, 0);
        c = __builtin_amdgcn_mfma_f32_16x16x32_f16(a[m][1].h8, b[ct][1].h8, c, 0, 0, 0);
        acc[m][ct] = c;
      }
  }
  {
    float bv0 = b1[col0], bv1 = b1[col1];
    #pragma unroll
    for (int m = 0; m < 2; m++)
      #pragma unroll
      for (int r = 0; r < 4; r++){
        acc[m][0][r] += bv0; acc[m][1][r] += bv1;
        float a0 = acc[m][0][r], a1 = acc[m][1][r];
        float s1 = a0 + a1, s2 = a0*a0 + a1*a1;
        #pragma unroll
        for (int o = 1; o < 16; o <<= 1){ s1 += __shfl_xor(s1, o, 64); s2 += __shfl_xor(s2, o, 64); }
        if (lc == 0){ int row = m*16 + lg*4 + r; red[w][row][0] = s1; red[w][row][1] = s2; }
      }
  }
  __syncthreads();
  if (t < 32){
    float s1 = red[0][t][0] + red[1][t][0] + red[2][t][0] + red[3][t][0];
    float s2 = red[0][t][1] + red[1][t][1] + red[2][t][1] + red[3][t][1];
    float mu = s1 * (1.f/128.f);
    float var = s2 * (1.f/128.f) - mu*mu;
    stat[t][0] = mu;
    stat[t][1] = rsqrtf(fmaxf(var, 0.f) + 1e-5f);
  }
  __syncthreads();
  {
    float g1a = g1[col0], g1b = g1[col1], b1a = bt1[col0], b1b = bt1[col1];
    #pragma unroll
    for (int m = 0; m < 2; m++)
      #pragma unroll
      for (int r = 0; r < 4; r++){
        int row = m*16 + lg*4 + r;
        float mu = stat[row][0], inv = stat[row][1];
        float y0 = (acc[m][0][r] - mu)*inv*g1a + b1a;
        float y1 = (acc[m][1][r] - mu)*inv*g1b + b1b;
        hs[row*136 + col0] = __float2half_rn(softplus_f(y0));
        hs[row*136 + col1] = __float2half_rn(softplus_f(y1));
      }
  }
  __syncthreads();

  // ---- layer 2: 128 -> 128 via MFMA ----
  f32x4 acc2[2][2];
  {
    HF b[2][4];
    const float4* wb = (const float4*)Wm2;
    #pragma unroll
    for (int ct = 0; ct < 2; ct++)
      #pragma unroll
      for (int kt = 0; kt < 4; kt++)
        b[ct][kt].f4 = wb[(((w*2 + ct)*4 + kt)*64) + lane];
    #pragma unroll
    for (int m = 0; m < 2; m++){
      f32x4 c0 = {0.f,0.f,0.f,0.f}, c1 = {0.f,0.f,0.f,0.f};
      #pragma unroll
      for (int kt = 0; kt < 4; kt++){
        HF av; av.f4 = *(const float4*)(hs + (m*16 + lc)*136 + kt*32 + lg*8);
        c0 = __builtin_amdgcn_mfma_f32_16x16x32_f16(av.h8, b[0][kt].h8, c0, 0, 0, 0);
        c1 = __builtin_amdgcn_mfma_f32_16x16x32_f16(av.h8, b[1][kt].h8, c1, 0, 0, 0);
      }
      acc2[m][0] = c0; acc2[m][1] = c1;
    }
  }
  {
    float bv0 = b2[col0], bv1 = b2[col1];
    #pragma unroll
    for (int m = 0; m < 2; m++)
      #pragma unroll
      for (int r = 0; r < 4; r++){
        acc2[m][0][r] += bv0; acc2[m][1][r] += bv1;
        float a0 = acc2[m][0][r], a1 = acc2[m][1][r];
        float s1 = a0 + a1, s2 = a0*a0 + a1*a1;
        #pragma unroll
        for (int o = 1; o < 16; o <<= 1){ s1 += __shfl_xor(s1, o, 64); s2 += __shfl_xor(s2, o, 64); }
        if (lc == 0){ int row = m*16 + lg*4 + r; red[w][row][0] = s1; red[w][row][1] = s2; }
      }
  }
  __syncthreads();
  if (t < 32){
    float s1 = red[0][t][0] + red[1][t][0] + red[2][t][0] + red[3][t][0];
    float s2 = red[0][t][1] + red[1][t][1] + red[2][t][1] + red[3][t][1];
    float mu = s1 * (1.f/128.f);
    float var = s2 * (1.f/128.f) - mu*mu;
    stat[t][0] = mu;
    stat[t][1] = rsqrtf(fmaxf(var, 0.f) + 1e-5f);
  }
  __syncthreads();
  {
    float g2a = g2[col0], g2b = g2[col1], b2a = bt2[col0], b2b = bt2[col1];
    float woa = Wout[col0], wob = Wout[col1];
    #pragma unroll
    for (int m = 0; m < 2; m++)
      #pragma unroll
      for (int r = 0; r < 4; r++){
        int row = m*16 + lg*4 + r;
        float mu = stat[row][0], inv = stat[row][1];
        float e = softplus_f((acc2[m][0][r] - mu)*inv*g2a + b2a) * woa
                + softplus_f((acc2[m][1][r] - mu)*inv*g2b + b2b) * wob;
        #pragma unroll
        for (int o = 1; o < 16; o <<= 1) e += __shfl_xor(e, o, 64);
        if (lc == 0) red[w][row][0] = e;
      }
  }
  __syncthreads();
  if (t < 32) es[t] = red[0][t][0] + red[1][t][0] + red[2][t][0] + red[3][t][0];
  __syncthreads();

  if (t < 32){
    int node = n0 + t;
    int g = batch[node];
    bool head = (t == 0) || (batch[node-1] != g);
    if (head){
      float s = 0.f; int c = 0;
      int j = t;
      while (j < 32 && batch[n0+j] == g){ s += es[j]; c++; j++; }
      atomicAdd(&gsum[g], s);
      atomicAdd(&gcnt[g], c);
    }
  }
}

// ---------------- final ----------------
__global__ void k_final(const float* __restrict__ gsum, const int* __restrict__ gcnt,
                        const float* __restrict__ bout, float* __restrict__ out){
  int g = threadIdx.x;
  if (g < NGRAPH)
    out[g] = gsum[g] / fmaxf((float)gcnt[g], 1.f) + bout[0];
}

extern "C" void kernel_launch(void* const* d_in, const int* in_sizes, int n_in,
                              void* d_out, int out_size, void* d_ws, size_t ws_size,
                              hipStream_t stream){
  const int*   numbers = (const int*)d_in[0];
  const int*   eidx    = (const int*)d_in[1];
  const float* elen    = (const float*)d_in[2];
  const int*   batch   = (const int*)d_in[3];
  const float* embed   = (const float*)d_in[4];
  const float* Wf      = (const float*)d_in[5];
  const float* bf      = (const float*)d_in[6];
  const float* Ws      = (const float*)d_in[7];
  const float* bs      = (const float*)d_in[8];
  const float* lng     = (const float*)d_in[9];
  const float* lnb     = (const float*)d_in[10];
  const float* W1      = (const float*)d_in[11];
  const float* b1      = (const float*)d_in[12];
  const float* g1      = (const float*)d_in[13];
  const float* bt1     = (const float*)d_in[14];
  const float* W2      = (const float*)d_in[15];
  const float* b2      = (const float*)d_in[16];
  const float* g2      = (const float*)d_in[17];
  const float* bt2     = (const float*)d_in[18];
  const float* Wout    = (const float*)d_in[19];
  const float* bout    = (const float*)d_in[20];
  const int* src = eidx;
  const int* tgt = eidx + NEDGES;

  float*   x    = (float*)d_ws;                          // N*64 f32
  __half2* pqh  = (__half2*)(x + (size_t)NNODES*64);     // N*128 half2
  __half*  Gth  = (__half*)(pqh + (size_t)NNODES*128);   // 3*TBL*128 half
  __half*  WmC  = Gth + (size_t)3*TBL*128;               // 3*16384 half
  __half*  Wm1  = WmC + (size_t)3*16384;                 // 8192 half
  __half*  Wm2  = Wm1 + 8192;                            // 16384 half
  float2*  lutg = (float2*)(Wm2 + 16384);                // 1024 float2 (512 used)
  int2*    ep   = (int2*)(lutg + 1024);                  // NCHUNK*CAP int2 (final CSR)
  int2*    ebuf = ep + (size_t)NCHUNK*CAP;               // NCHUNK*CAP int2 (staging)
  int*     offs = (int*)(ebuf + (size_t)NCHUNK*CAP);     // N
  int*     deg  = offs + NNODES;                         // N
  int*     ccur = deg + NNODES;                          // 256
  float*   gsum = (float*)(ccur + 256);                  // 256
  int*     gcnt = (int*)(gsum + NGRAPH);                 // 256
  float*   out  = (float*)d_out;

  k_prep  <<<257 + (NNODES*64+255)/256, 256, 0, stream>>>(
            numbers, embed, x, Wf, Ws, WmC, W1, W2, Wm1, Wm2,
            lutg, ccur, gsum, gcnt);

  k_bin   <<<(NEDGES+2047)/2048, 256, 0, stream>>>(src, tgt, elen, ccur, ebuf);
  k_fine  <<<NCHUNK, 512, 0, stream>>>(ccur, ebuf, ep, offs, deg);

  k_gauss <<<3*TBL, 128, 0, stream>>>(Wf, bf, Ws, bs, Gth);

  for (int i = 0; i < NCONV; i++){
    k_ntrans<<<NNODES/32, 256, 0, stream>>>(x, WmC + (size_t)i*16384, pqh);
    k_edge  <<<NNODES/4, 256, 0, stream>>>(pqh, offs, deg, ep,
                                           Gth + (size_t)i*TBL*128,
                                           lng + i*64, lnb + i*64, lutg, x);
  }

  k_head<<<NNODES/32, 256, 0, stream>>>(x, Wm1, b1, g1, bt1,
                                        Wm2, b2, g2, bt2, Wout, batch, gsum, gcnt);
  k_final<<<1, 256, 0, stream>>>(gsum, gcnt, bout, out);
}

// Round 10
// 537.155 us; speedup vs baseline: 1.0225x; 1.0091x over previous
//
#include <hip/hip_runtime.h>
#include <hip/hip_fp16.h>
#include <math.h>

#define NNODES 100000
#define NEDGES 1600000
#define NGRAPH 256
#define NCONV  3
#define TBL    4096
#define CHUNK  512
#define NCHUNK 196         // ceil(100000/512)
#define CAP    9216        // fixed per-chunk region capacity (mean 8163 + 11 sigma)
#define R_MIN_ 1.0f
#define R_MAX_ 6.0f
#define LOG2E  1.4426950408889634f

typedef _Float16 f16x8 __attribute__((ext_vector_type(8)));
typedef float f32x4 __attribute__((ext_vector_type(4)));
union HF { float4 f4; f16x8 h8; __half2 q[4]; };

__device__ __forceinline__ float softplus_f(float x){
  return fmaxf(x, 0.f) + __logf(1.f + __expf(-fabsf(x)));
}

// ---------------- fused prep ----------------
// b in [0,64):    Wm1/Wm2 MFMA b-fragment pack
// b == 64:        softplus LUT + ccur/gsum/gcnt init
// b in [65,257):  conv weight pack WmC
// b >= 257:       embedding gather
__global__ void k_prep(const int* __restrict__ numbers, const float* __restrict__ embed,
                       float* __restrict__ x,
                       const float* __restrict__ Wf, const float* __restrict__ Ws,
                       __half* __restrict__ WmC,
                       const float* __restrict__ W1, const float* __restrict__ W2,
                       __half* __restrict__ Wm1, __half* __restrict__ Wm2,
                       float2* __restrict__ lutg, int* __restrict__ ccur,
                       float* __restrict__ gsum, int* __restrict__ gcnt){
  int b = blockIdx.x, t = threadIdx.x;
  if (b >= 257){
    int i = (b - 257)*256 + t;
    if (i < NNODES*64){
      int n = i >> 6, c = i & 63;
      x[i] = embed[numbers[n]*64 + c];
    }
    return;
  }
  if (b >= 65){
    // WmC[i]: [ct(16)][kt(2)][lane(64)][e(8)]; cols 0..63 pf, 64..127 ps, 128..191 qf, 192..255 qs
    int idx = (b - 65)*256 + t;       // < 3*16384
    int i = idx / 16384;
    int rem = idx & 16383;
    int ct = rem >> 10;
    int kt = (rem >> 9) & 1;
    int lane = (rem >> 3) & 63;
    int e = rem & 7;
    int col = ct*16 + (lane & 15);
    int part = col >> 6;
    int ch = col & 63;
    int k = kt*32 + (lane >> 4)*8 + e;
    int row = ((part >> 1) ? 64 : 0) + k;
    const float* W = ((part & 1) ? Ws : Wf) + i*192*64;
    WmC[idx] = __float2half_rn(W[row*64 + ch]);
    return;
  }
  if (b == 64){
    __shared__ float cv[513];
    for (int i = t; i < 513; i += 256){
      float z = -16.f + (float)i * (1.f/16.f);
      cv[i] = log2f(1.f + exp2f(z));
    }
    __syncthreads();
    for (int i = t; i < 512; i += 256)
      lutg[i] = make_float2(cv[i], cv[i+1]-cv[i]);
    if (t < NCHUNK) ccur[t] = t * CAP;
    if (t < NGRAPH){ gsum[t] = 0.f; gcnt[t] = 0; }
    return;
  }
  int i = b*256 + t;                 // [0, 16384)
  if (i < 8192){
    int ct = i >> 10;
    int kt = (i >> 9) & 1;
    int lane = (i >> 3) & 63;
    int e = i & 7;
    int k = kt*32 + (lane>>4)*8 + e;
    int c = ct*16 + (lane&15);
    Wm1[i] = __float2half_rn(W1[k*128 + c]);
  }
  {
    int ct = i >> 11;
    int kt = (i >> 9) & 3;
    int lane = (i >> 3) & 63;
    int e = i & 7;
    int k = kt*32 + (lane>>4)*8 + e;
    int c = ct*16 + (lane&15);
    Wm2[i] = __float2half_rn(W2[k*128 + c]);
  }
}

// ---------------- pass 1: bin edges into fixed-stride chunk regions ----------------
__global__ void k_bin(const int* __restrict__ src, const int* __restrict__ tgt,
                      const float* __restrict__ elen, int* ccur,
                      int2* __restrict__ eb){
  __shared__ int lcnt[NCHUNK];
  __shared__ int lbase[NCHUNK];
  __shared__ int loff[NCHUNK];
  int t = threadIdx.x;
  int e0 = blockIdx.x * 2048;
  if (t < NCHUNK){ lcnt[t] = 0; loff[t] = 0; }
  __syncthreads();
  #pragma unroll
  for (int k = 0; k < 8; k++){
    int e = e0 + k*256 + t;
    if (e < NEDGES) atomicAdd(&lcnt[src[e] / CHUNK], 1);
  }
  __syncthreads();
  if (t < NCHUNK && lcnt[t] > 0) lbase[t] = atomicAdd(&ccur[t], lcnt[t]);
  __syncthreads();
  #pragma unroll
  for (int k = 0; k < 8; k++){
    int e = e0 + k*256 + t;
    if (e < NEDGES){
      int s = src[e];
      int c = s / CHUNK;
      int r = atomicAdd(&loff[c], 1);
      float key = (elen[e] - R_MIN_) * ((float)(TBL-1)/(R_MAX_-R_MIN_));
      key = fmaxf(key, 0.f);
      int idx = (int)(key + 0.5f);
      if (idx > TBL-1) idx = TBL-1;
      eb[lbase[c] + r] = make_int2(((s & (CHUNK-1)) << 17) | tgt[e], idx);
    }
  }
}

// ---------------- pass 2: fine scatter; builds offs + deg via LDS count+scan ----------------
// ep records are PRE-SHIFTED byte offsets: .x = tgt<<9, .y = idx<<8
// (paid once here; k_edge reads each record 3x and skips the shifts)
__global__ void k_fine(const int* __restrict__ ccur, const int2* __restrict__ eb,
                       int2* __restrict__ ep, int* __restrict__ offs,
                       int* __restrict__ deg){
  __shared__ int lcnt[CHUNK];
  __shared__ int lsc[CHUNK];
  int c = blockIdx.x;
  int t = threadIdx.x;                    // 512 threads
  int n0 = c * CHUNK;
  int n1 = min(n0 + CHUNK, NNODES);
  int cnt = n1 - n0;
  int j0 = c * CAP;
  int j1 = ccur[c];                       // j0 + edges in this chunk
  lcnt[t] = 0;
  __syncthreads();
  for (int e = j0 + t; e < j1; e += 512)
    atomicAdd(&lcnt[((unsigned)eb[e].x) >> 17], 1);
  __syncthreads();
  lsc[t] = lcnt[t];
  __syncthreads();
  for (int d = 1; d < 512; d <<= 1){
    int v = (t >= d) ? lsc[t-d] : 0;
    __syncthreads();
    lsc[t] += v;
    __syncthreads();
  }
  int excl = lsc[t] - lcnt[t];
  if (t < cnt){ offs[n0 + t] = j0 + excl; deg[n0 + t] = lcnt[t]; }
  __syncthreads();
  lcnt[t] = j0 + excl;                    // reuse as cursors
  __syncthreads();
  for (int e = j0 + t; e < j1; e += 512){
    int2 rec = eb[e];
    int sl = ((unsigned)rec.x) >> 17;
    int pos = atomicAdd(&lcnt[sl], 1);
    ep[pos] = make_int2((rec.x & 0x1FFFF) << 9, rec.y << 8);
  }
}

// ---------------- Gaussian table, fp16, PRE-SCALED by log2(e) ----------------
__global__ void k_gauss(const float* __restrict__ Wf, const float* __restrict__ bf,
                        const float* __restrict__ Ws, const float* __restrict__ bs,
                        __half* __restrict__ Gth){
  __shared__ float attr[64];
  int bi = blockIdx.x;                  // 3*TBL
  int i = bi / TBL, r = bi % TBL;
  int t = threadIdx.x;                  // 128
  float d = R_MIN_ + (R_MAX_-R_MIN_) * (float)r / (float)(TBL-1);
  if (t < 64){
    float cj = 1.f + 5.f * (float)t / 63.f;
    float u = (d - cj) * (64.f/5.f);
    attr[t] = __expf(-0.5f*u*u);
  }
  __syncthreads();
  int c = t >> 1;
  int side = t & 1;
  const float* W = (side ? Ws : Wf) + i*192*64 + 128*64 + c;
  float acc = (side ? bs : bf)[i*64 + c];
  #pragma unroll 8
  for (int j = 0; j < 64; j++) acc = fmaf(attr[j], W[j*64], acc);
  Gth[((size_t)i*TBL + r)*128 + t] = __float2half_rn(acc * LOG2E);
}

// ---------------- node transform via MFMA: 32 nodes x 256 cols ----------------
__global__ void k_ntrans(const float* __restrict__ x, const __half* __restrict__ WmC,
                         __half2* __restrict__ pqh){
  __shared__ __half xh[32*72];      // 4.5 KB, row stride 72
  int n0 = blockIdx.x * 32;         // 3125 blocks
  int t = threadIdx.x;              // 256 = 4 waves
  int w = t >> 6, lane = t & 63;
  int lg = lane >> 4, lc = lane & 15;
  {
    int n = t >> 3, g = t & 7;
    const float4* xp = (const float4*)(x + (size_t)(n0 + n)*64 + g*8);
    float4 a = xp[0], b = xp[1];
    HF hh;
    hh.q[0] = __float22half2_rn(make_float2(a.x, a.y));
    hh.q[1] = __float22half2_rn(make_float2(a.z, a.w));
    hh.q[2] = __float22half2_rn(make_float2(b.x, b.y));
    hh.q[3] = __float22half2_rn(make_float2(b.z, b.w));
    *(float4*)(xh + n*72 + g*8) = hh.f4;
  }
  __syncthreads();
  HF a[2][2];
  #pragma unroll
  for (int m = 0; m < 2; m++)
    #pragma unroll
    for (int kt = 0; kt < 2; kt++)
      a[m][kt].f4 = *(const float4*)(xh + (m*16 + lc)*72 + kt*32 + lg*8);
  const float4* wb = (const float4*)WmC;
  f32x4 acc[4][2];                  // [part][m]
  #pragma unroll
  for (int p4 = 0; p4 < 4; p4++){
    int ct = p4*4 + w;
    HF b0, b1;
    b0.f4 = wb[(ct*2 + 0)*64 + lane];
    b1.f4 = wb[(ct*2 + 1)*64 + lane];
    #pragma unroll
    for (int m = 0; m < 2; m++){
      f32x4 c = {0.f, 0.f, 0.f, 0.f};
      c = __builtin_amdgcn_mfma_f32_16x16x32_f16(a[m][0].h8, b0.h8, c, 0, 0, 0);
      c = __builtin_amdgcn_mfma_f32_16x16x32_f16(a[m][1].h8, b1.h8, c, 0, 0, 0);
      acc[p4][m] = c;
    }
  }
  #pragma unroll
  for (int m = 0; m < 2; m++)
    #pragma unroll
    for (int r = 0; r < 4; r++){
      int node = n0 + m*16 + lg*4 + r;
      int ch = w*16 + lc;
      __half2 hp = __floats2half2_rn(acc[0][m][r]*LOG2E, acc[1][m][r]*LOG2E);
      __half2 hq = __floats2half2_rn(acc[2][m][r]*LOG2E, acc[3][m][r]*LOG2E);
      pqh[(size_t)node*128 + ch]      = hp;
      pqh[(size_t)node*128 + 64 + ch] = hq;
    }
}

// ---------------- edge pass: wave per node; analytic sigmoid + softplus LUT ----------------
// Records pre-shifted (tgt<<9, idx<<8). Sigmoid via hoisted Cf = 2^-pf:
//   sig = rcp(fmaf(Cf, 2^-z.x, 1))   (exp2's neg folds into src modifier)
// sp/ln2 = max(zs, T_lut(zs))
__global__ void k_edge(const __half2* __restrict__ pqh,
                       const int* __restrict__ offs, const int* __restrict__ deg,
                       const int2* __restrict__ ep,
                       const __half* __restrict__ Gth, const float* __restrict__ lng,
                       const float* __restrict__ lnb, const float2* __restrict__ lutg,
                       float* __restrict__ x){
  __shared__ float2 lut[512];       // 4 KB softplus-T table
  {
    ((float4*)lut)[threadIdx.x] = ((const float4*)lutg)[threadIdx.x];
  }
  __syncthreads();
  int wid  = (blockIdx.x*256 + threadIdx.x) >> 6;
  int lane = threadIdx.x & 63;
  int n = wid;
  int j0 = __builtin_amdgcn_readfirstlane(offs[n]);
  int dg = __builtin_amdgcn_readfirstlane(deg[n]);
  int j1 = j0 + dg;
  int nfull = dg >> 3;
  int2 eb8[8];
  if (nfull > 0){
    #pragma unroll
    for (int i = 0; i < 8; i++) eb8[i] = ep[j0 + i];
  }
  float2 pp = __half22float2(pqh[(size_t)n*128 + lane]);
  float pf = pp.x, ps = pp.y;
  float Cf = __builtin_amdgcn_exp2f(-pf);   // 2^-pf, hoisted (validated R1-R4)
  float pso = fmaf(ps, 16.f, 256.f);        // T-table index offset (f32-precise p add)
  const char* pqb = (const char*)pqh;
  const char* gtb = (const char*)Gth;
  unsigned qob = 256u + ((unsigned)lane << 2);
  unsigned lob = (unsigned)lane << 2;
  float acc = 0.f;
  int u = j0;
  for (int b = 0; b < nfull; b++){
    __half2 qr[8], gr[8];
    #pragma unroll
    for (int i = 0; i < 8; i++){
      qr[i] = *(const __half2*)(pqb + ((unsigned)eb8[i].x + qob));
      gr[i] = *(const __half2*)(gtb + ((unsigned)eb8[i].y + lob));
    }
    if (b + 1 < nfull){
      #pragma unroll
      for (int i = 0; i < 8; i++) eb8[i] = ep[u + 8 + i];
    }
    #pragma unroll
    for (int i = 0; i < 8; i++){
      float2 z = __half22float2(__hadd2(qr[i], gr[i]));
      float sig = __builtin_amdgcn_rcpf(fmaf(Cf, __builtin_amdgcn_exp2f(-z.x), 1.f));
      float xj = __builtin_amdgcn_fmed3f(fmaf(z.y, 16.f, pso), 0.f, 511.36f);
      int i2 = (int)xj;
      float f2 = __builtin_amdgcn_fractf(xj);
      float2 e2 = lut[i2];
      float zs = ps + z.y;
      float sp = fmaxf(zs, fmaf(e2.y, f2, e2.x));
      acc = fmaf(sig, sp, acc);
    }
    u += 8;
  }
  for (; u < j1; u++){
    int2 e = ep[u];
    __half2 q = *(const __half2*)(pqb + ((unsigned)e.x + qob));
    __half2 g = *(const __half2*)(gtb + ((unsigned)e.y + lob));
    float2 z = __half22float2(__hadd2(q, g));
    float sig = __builtin_amdgcn_rcpf(fmaf(Cf, __builtin_amdgcn_exp2f(-z.x), 1.f));
    float xj = __builtin_amdgcn_fmed3f(fmaf(z.y, 16.f, pso), 0.f, 511.36f);
    int i2 = (int)xj;
    float f2 = __builtin_amdgcn_fractf(xj);
    float2 e2 = lut[i2];
    float zs = ps + z.y;
    float sp = fmaxf(zs, fmaf(e2.y, f2, e2.x));
    acc = fmaf(sig, sp, acc);
  }
  float s1 = acc, s2 = acc*acc;
  #pragma unroll
  for (int o = 32; o > 0; o >>= 1){ s1 += __shfl_xor(s1, o, 64); s2 += __shfl_xor(s2, o, 64); }
  float mu  = s1 * (1.f/64.f);
  float var = s2 * (1.f/64.f) - mu*mu;
  float inv = rsqrtf(fmaxf(var, 0.f) + 1e-5f);
  float y = (acc - mu) * inv * lng[lane] + lnb[lane];
  x[(size_t)n*64 + lane] += y;
}

// ---------------- fused head: MFMA 16x16x32 f16 GEMMs + LN/softplus epilogues ----------------
__global__ void k_head(const float* __restrict__ x,
                       const __half* __restrict__ Wm1, const float* __restrict__ b1,
                       const float* __restrict__ g1, const float* __restrict__ bt1,
                       const __half* __restrict__ Wm2, const float* __restrict__ b2,
                       const float* __restrict__ g2, const float* __restrict__ bt2,
                       const float* __restrict__ Wout, const int* __restrict__ batch,
                       float* gsum, int* gcnt){
  __shared__ __half xh[32*72];      // 4.5 KB
  __shared__ __half hs[32*136];     // 8.5 KB
  __shared__ float red[4][32][2];
  __shared__ float stat[32][2];
  __shared__ float es[32];
  int n0 = blockIdx.x * 32;         // 3125 blocks
  int t = threadIdx.x;              // 256
  int w = t >> 6, lane = t & 63;
  int lg = lane >> 4, lc = lane & 15;
  int col0 = w*32 + lc, col1 = w*32 + 16 + lc;

  {
    int n = t >> 3, g = t & 7;
    const float4* xp = (const float4*)(x + (size_t)(n0 + n)*64 + g*8);
    float4 a = xp[0], b = xp[1];
    HF hh;
    hh.q[0] = __float22half2_rn(make_float2(a.x, a.y));
    hh.q[1] = __float22half2_rn(make_float2(a.z, a.w));
    hh.q[2] = __float22half2_rn(make_float2(b.x, b.y));
    hh.q[3] = __float22half2_rn(make_float2(b.z, b.w));
    *(float4*)(xh + n*72 + g*8) = hh.f4;
  }
  __syncthreads();

  // ---- layer 1: 64 -> 128 via MFMA ----
  f32x4 acc[2][2];
  {
    HF a[2][2], b[2][2];
    #pragma unroll
    for (int m = 0; m < 2; m++)
      #pragma unroll
      for (int kt = 0; kt < 2; kt++)
        a[m][kt].f4 = *(const float4*)(xh + (m*16 + lc)*72 + kt*32 + lg*8);
    const float4* wb = (const float4*)Wm1;
    #pragma unroll
    for (int ct = 0; ct < 2; ct++)
      #pragma unroll
      for (int kt = 0; kt < 2; kt++)
        b[ct][kt].f4 = wb[(((w*2 + ct)*2 + kt)*64) + lane];
    #pragma unroll
    for (int m = 0; m < 2; m++)
      #pragma unroll
      for (int ct = 0; ct < 2; ct++){
        f32x4 c = {0.f, 0.f, 0.f, 0.f};
        c = __builtin_amdgcn_mfma_f32_16x16x32_f16(a[m][0].h8, b[ct][0].h8, c, 0, 0, 0);
        c = __builtin_amdgcn_mfma_f32_16x16x32_f16(a[m][1].h8, b[ct][1].h8, c, 0, 0, 0);
        acc[m][ct] = c;
      }
  }
  {
    float bv0 = b1[col0], bv1 = b1[col1];
    #pragma unroll
    for (int m = 0; m < 2; m++)
      #pragma unroll
      for (int r = 0; r < 4; r++){
        acc[m][0][r] += bv0; acc[m][1][r] += bv1;
        float a0 = acc[m][0][r], a1 = acc[m][1][r];
        float s1 = a0 + a1, s2 = a0*a0 + a1*a1;
        #pragma unroll
        for (int o = 1; o < 16; o <<= 1){ s1 += __shfl_xor(s1, o, 64); s2 += __shfl_xor(s2, o, 64); }
        if (lc == 0){ int row = m*16 + lg*4 + r; red[w][row][0] = s1; red[w][row][1] = s2; }
      }
  }
  __syncthreads();
  if (t < 32){
    float s1 = red[0][t][0] + red[1][t][0] + red[2][t][0] + red[3][t][0];
    float s2 = red[0][t][1] + red[1][t][1] + red[2][t][1] + red[3][t][1];
    float mu = s1 * (1.f/128.f);
    float var = s2 * (1.f/128.f) - mu*mu;
    stat[t][0] = mu;
    stat[t][1] = rsqrtf(fmaxf(var, 0.f) + 1e-5f);
  }
  __syncthreads();
  {
    float g1a = g1[col0], g1b = g1[col1], b1a = bt1[col0], b1b = bt1[col1];
    #pragma unroll
    for (int m = 0; m < 2; m++)
      #pragma unroll
      for (int r = 0; r < 4; r++){
        int row = m*16 + lg*4 + r;
        float mu = stat[row][0], inv = stat[row][1];
        float y0 = (acc[m][0][r] - mu)*inv*g1a + b1a;
        float y1 = (acc[m][1][r] - mu)*inv*g1b + b1b;
        hs[row*136 + col0] = __float2half_rn(softplus_f(y0));
        hs[row*136 + col1] = __float2half_rn(softplus_f(y1));
      }
  }
  __syncthreads();

  // ---- layer 2: 128 -> 128 via MFMA ----
  f32x4 acc2[2][2];
  {
    HF b[2][4];
    const float4* wb = (const float4*)Wm2;
    #pragma unroll
    for (int ct = 0; ct < 2; ct++)
      #pragma unroll
      for (int kt = 0; kt < 4; kt++)
        b[ct][kt].f4 = wb[(((w*2 + ct)*4 + kt)*64) + lane];
    #pragma unroll
    for (int m = 0; m < 2; m++){
      f32x4 c0 = {0.f,0.f,0.f,0.f}, c1 = {0.f,0.f,0.f,0.f};
      #pragma unroll
      for (int kt = 0; kt < 4; kt++){
        HF av; av.f4 = *(const float4*)(hs + (m*16 + lc)*136 + kt*32 + lg*8);
        c0 = __builtin_amdgcn_mfma_f32_16x16x32_f16(av.h8, b[0][kt].h8, c0, 0, 0, 0);
        c1 = __builtin_amdgcn_mfma_f32_16x16x32_f16(av.h8, b[1][kt].h8, c1, 0, 0, 0);
      }
      acc2[m][0] = c0; acc2[m][1] = c1;
    }
  }
  {
    float bv0 = b2[col0], bv1 = b2[col1];
    #pragma unroll
    for (int m = 0; m < 2; m++)
      #pragma unroll
      for (int r = 0; r < 4; r++){
        acc2[m][0][r] += bv0; acc2[m][1][r] += bv1;
        float a0 = acc2[m][0][r], a1 = acc2[m][1][r];
        float s1 = a0 + a1, s2 = a0*a0 + a1*a1;
        #pragma unroll
        for (int o = 1; o < 16; o <<= 1){ s1 += __shfl_xor(s1, o, 64); s2 += __shfl_xor(s2, o, 64); }
        if (lc == 0){ int row = m*16 + lg*4 + r; red[w][row][0] = s1; red[w][row][1] = s2; }
      }
  }
  __syncthreads();
  if (t < 32){
    float s1 = red[0][t][0] + red[1][t][0] + red[2][t][0] + red[3][t][0];
    float s2 = red[0][t][1] + red[1][t][1] + red[2][t][1] + red[3][t][1];
    float mu = s1 * (1.f/128.f);
    float var = s2 * (1.f/128.f) - mu*mu;
    stat[t][0] = mu;
    stat[t][1] = rsqrtf(fmaxf(var, 0.f) + 1e-5f);
  }
  __syncthreads();
  {
    float g2a = g2[col0], g2b = g2[col1], b2a = bt2[col0], b2b = bt2[col1];
    float woa = Wout[col0], wob = Wout[col1];
    #pragma unroll
    for (int m = 0; m < 2; m++)
      #pragma unroll
      for (int r = 0; r < 4; r++){
        int row = m*16 + lg*4 + r;
        float mu = stat[row][0], inv = stat[row][1];
        float e = softplus_f((acc2[m][0][r] - mu)*inv*g2a + b2a) * woa
                + softplus_f((acc2[m][1][r] - mu)*inv*g2b + b2b) * wob;
        #pragma unroll
        for (int o = 1; o < 16; o <<= 1) e += __shfl_xor(e, o, 64);
        if (lc == 0) red[w][row][0] = e;
      }
  }
  __syncthreads();
  if (t < 32) es[t] = red[0][t][0] + red[1][t][0] + red[2][t][0] + red[3][t][0];
  __syncthreads();

  if (t < 32){
    int node = n0 + t;
    int g = batch[node];
    bool head = (t == 0) || (batch[node-1] != g);
    if (head){
      float s = 0.f; int c = 0;
      int j = t;
      while (j < 32 && batch[n0+j] == g){ s += es[j]; c++; j++; }
      atomicAdd(&gsum[g], s);
      atomicAdd(&gcnt[g], c);
    }
  }
}

// ---------------- final ----------------
__global__ void k_final(const float* __restrict__ gsum, const int* __restrict__ gcnt,
                        const float* __restrict__ bout, float* __restrict__ out){
  int g = threadIdx.x;
  if (g < NGRAPH)
    out[g] = gsum[g] / fmaxf((float)gcnt[g], 1.f) + bout[0];
}

extern "C" void kernel_launch(void* const* d_in, const int* in_sizes, int n_in,
                              void* d_out, int out_size, void* d_ws, size_t ws_size,
                              hipStream_t stream){
  const int*   numbers = (const int*)d_in[0];
  const int*   eidx    = (const int*)d_in[1];
  const float* elen    = (const float*)d_in[2];
  const int*   batch   = (const int*)d_in[3];
  const float* embed   = (const float*)d_in[4];
  const float* Wf      = (const float*)d_in[5];
  const float* bf      = (const float*)d_in[6];
  const float* Ws      = (const float*)d_in[7];
  const float* bs      = (const float*)d_in[8];
  const float* lng     = (const float*)d_in[9];
  const float* lnb     = (const float*)d_in[10];
  const float* W1      = (const float*)d_in[11];
  const float* b1      = (const float*)d_in[12];
  const float* g1      = (const float*)d_in[13];
  const float* bt1     = (const float*)d_in[14];
  const float* W2      = (const float*)d_in[15];
  const float* b2      = (const float*)d_in[16];
  const float* g2      = (const float*)d_in[17];
  const float* bt2     = (const float*)d_in[18];
  const float* Wout    = (const float*)d_in[19];
  const float* bout    = (const float*)d_in[20];
  const int* src = eidx;
  const int* tgt = eidx + NEDGES;

  float*   x    = (float*)d_ws;                          // N*64 f32
  __half2* pqh  = (__half2*)(x + (size_t)NNODES*64);     // N*128 half2
  __half*  Gth  = (__half*)(pqh + (size_t)NNODES*128);   // 3*TBL*128 half
  __half*  WmC  = Gth + (size_t)3*TBL*128;               // 3*16384 half
  __half*  Wm1  = WmC + (size_t)3*16384;                 // 8192 half
  __half*  Wm2  = Wm1 + 8192;                            // 16384 half
  float2*  lutg = (float2*)(Wm2 + 16384);                // 1024 float2 (512 used)
  int2*    ep   = (int2*)(lutg + 1024);                  // NCHUNK*CAP int2 (final CSR)
  int2*    ebuf = ep + (size_t)NCHUNK*CAP;               // NCHUNK*CAP int2 (staging)
  int*     offs = (int*)(ebuf + (size_t)NCHUNK*CAP);     // N
  int*     deg  = offs + NNODES;                         // N
  int*     ccur = deg + NNODES;                          // 256
  float*   gsum = (float*)(ccur + 256);                  // 256
  int*     gcnt = (int*)(gsum + NGRAPH);                 // 256
  float*   out  = (float*)d_out;

  k_prep  <<<257 + (NNODES*64+255)/256, 256, 0, stream>>>(
            numbers, embed, x, Wf, Ws, WmC, W1, W2, Wm1, Wm2,
            lutg, ccur, gsum, gcnt);

  k_bin   <<<(NEDGES+2047)/2048, 256, 0, stream>>>(src, tgt, elen, ccur, ebuf);
  k_fine  <<<NCHUNK, 512, 0, stream>>>(ccur, ebuf, ep, offs, deg);

  k_gauss <<<3*TBL, 128, 0, stream>>>(Wf, bf, Ws, bs, Gth);

  for (int i = 0; i < NCONV; i++){
    k_ntrans<<<NNODES/32, 256, 0, stream>>>(x, WmC + (size_t)i*16384, pqh);
    k_edge  <<<NNODES/4, 256, 0, stream>>>(pqh, offs, deg, ep,
                                           Gth + (size_t)i*TBL*128,
                                           lng + i*64, lnb + i*64, lutg, x);
  }

  k_head<<<NNODES/32, 256, 0, stream>>>(x, Wm1, b1, g1, bt1,
                                        Wm2, b2, g2, bt2, Wout, batch, gsum, gcnt);
  k_final<<<1, 256, 0, stream>>>(gsum, gcnt, bout, out);
}